// Round 9
// baseline (235.442 us; speedup 1.0000x reference)
//
#include <hip/hip_runtime.h>
#include <hip/hip_bf16.h>
#include <stdint.h>

#define TKS    4096   // tokens = 2*2048
#define KD     4096   // in_features
#define NSF    410    // split_f
#define NPARTS 10
#define OUTF   4096

typedef unsigned short u16;
typedef __attribute__((ext_vector_type(8))) short bf16x8;
typedef __attribute__((ext_vector_type(4))) float f32x4;

// ---- workspace layout (sx/gc carved from unused bsw slabs 448..511) ----
#define WS_XB  0                                     // u16[4096*4096]  granule bf16 x (32-row tiles)
#define WS_BSW ((size_t)TKS * KD * 2)                // u16[512*4096]   granule bf16 Wfc (64-row tiles)
#define WS_SX  (WS_BSW + (size_t)448 * 512 * 8 * 2)  // f32[4096*10]    sx
#define WS_GC  (WS_SX + (size_t)TKS * NPARTS * 4)    // f32[448*12]     G (cols 0..9) + c (col 10)
#define ZERO_U4 ((TKS * NPARTS + 448 * 12) * 4 / 16) // 11584 uint4 to zero (sx+gc)

__device__ inline u16 f2bf(float f) {
    union { __hip_bfloat16 b; u16 u; } cv;
    cv.b = __float2bfloat16(f);
    return cv.u;
}

// 64-row tile granule g in [0,512): slot=g>>6 = hi*4+ks*2+lo
// row = hi*32+lo*16+(g&15) ; col = ks*32+((g>>4)&3)*8   (conflict-free, proven)
__device__ inline int g_row(int g) { int s = g >> 6; return (s >> 2) * 32 + (s & 1) * 16 + (g & 15); }
__device__ inline int g_col(int g) { int s = g >> 6; return ((s >> 1) & 1) * 32 + ((g >> 4) & 3) * 8; }

// ============ retile: streaming retile only (low VGPR -> high occupancy) =====
// R8: split from the monolithic prep whose sx/G branch forced VGPR=124 onto
// 8640 streaming blocks (4 waves/SIMD cap -> 2.3 TB/s). Retile paths are
// ~30 VGPR. x-path batches 2 granules/thread, all loads before stores.
//   [0,4096)     retile_x : block = (tb, kt-pair), 2 granules/thread
//   [4096,4544)  retile_b : Wfc -> bsw (rows >= 410 zero)
//   [4544]       zero sx/gc tables (for selg's atomicAdd)
__global__ __launch_bounds__(256) void retile(const float* __restrict__ x,
                                              const float* __restrict__ Wfc,
                                              u16* __restrict__ xb,
                                              u16* __restrict__ bsw,
                                              uint4* __restrict__ zbase) {
    const int bid = blockIdx.x;
    const int tid = threadIdx.x;

    if (bid < 4096) {
        const int ktp = bid & 31, tb = bid >> 5;    // ktp 0..31, tb 0..127
        const int g = tid;
        const int slot = g >> 6;
        const int row = (slot & 1) * 16 + (g & 15);
        const int col = (slot >> 1) * 32 + ((g >> 4) & 3) * 8;
        const float* src = x + (size_t)(tb * 32 + row) * KD + ktp * 128 + col;
        float4 a0 = *(const float4*)src;
        float4 a1 = *(const float4*)(src + 4);
        float4 b0 = *(const float4*)(src + 64);
        float4 b1 = *(const float4*)(src + 68);
        u16 ha[8] = { f2bf(a0.x), f2bf(a0.y), f2bf(a0.z), f2bf(a0.w),
                      f2bf(a1.x), f2bf(a1.y), f2bf(a1.z), f2bf(a1.w) };
        u16 hb[8] = { f2bf(b0.x), f2bf(b0.y), f2bf(b0.z), f2bf(b0.w),
                      f2bf(b1.x), f2bf(b1.y), f2bf(b1.z), f2bf(b1.w) };
        *(uint4*)&xb[((size_t)(tb * 64 + ktp * 2 + 0) * 256 + g) * 8] = *(uint4*)ha;
        *(uint4*)&xb[((size_t)(tb * 64 + ktp * 2 + 1) * 256 + g) * 8] = *(uint4*)hb;

    } else if (bid < 4544) {
        const int b2 = bid - 4096;
        const int kt = b2 & 63, rb = b2 >> 6;       // rb 0..6
        u16* tout = bsw + ((size_t)(rb * 64 + kt) * 512) * 8;
#pragma unroll
        for (int j = 0; j < 2; ++j) {
            const int g = j * 256 + tid;
            const int r = rb * 64 + g_row(g);
            uint4 pk = make_uint4(0u, 0u, 0u, 0u);
            if (r < NSF) {
                const float* src = Wfc + (size_t)r * KD + kt * 64 + g_col(g);
                float4 v0 = *(const float4*)src;
                float4 v1 = *(const float4*)(src + 4);
                u16 h[8] = { f2bf(v0.x), f2bf(v0.y), f2bf(v0.z), f2bf(v0.w),
                             f2bf(v1.x), f2bf(v1.y), f2bf(v1.z), f2bf(v1.w) };
                pk = *(uint4*)h;
            }
            *(uint4*)&tout[(size_t)g * 8] = pk;
        }

    } else {
        // zero the sx + gc accumulation tables (contiguous region)
        for (int i = tid; i < ZERO_U4; i += 256)
            zbase[i] = make_uint4(0u, 0u, 0u, 0u);
    }
}

// ============ selg: sx and G/c partials, K-split x8, atomicAdd combine =======
// R8: the old 142 long blocks (K=4096 serial) were prep's latency tail.
// Now 1136 short blocks (K=512 each); x/Wfc are L3-warm from retile.
//   [0,1024)     sx partial : block (b3 = bid>>3, kc = bid&7), 32 tok
//   [1024,1136)  G  partial : block (fb = .. >>3, kc = ..&7), 32 f-rows
__global__ __launch_bounds__(256) void selg(const float* __restrict__ x,
                                            const float* __restrict__ Wsel,
                                            const float* __restrict__ bsel,
                                            const float* __restrict__ Wexp,
                                            const float* __restrict__ bexp,
                                            const float* __restrict__ Wfc,
                                            const float* __restrict__ bfc,
                                            float* __restrict__ sxb,
                                            float* __restrict__ gc) {
    const int bid = blockIdx.x;
    const int tid = threadIdx.x;
    const int w = tid >> 6, lane = tid & 63;

    if (bid < 1024) {
        const int b3 = bid >> 3, kc = bid & 7;      // b3 0..127, K-chunk kc*512..
        const int t0 = b3 * 32 + w * 8;
        float acc[8][NPARTS];
#pragma unroll
        for (int t = 0; t < 8; ++t)
#pragma unroll
            for (int n = 0; n < NPARTS; ++n) acc[t][n] = 0.f;

#pragma unroll
        for (int k4 = 0; k4 < 2; ++k4) {
            const int k = kc * 512 + k4 * 256 + lane * 4;
            float4 ws[NPARTS];
#pragma unroll
            for (int n = 0; n < NPARTS; ++n)
                ws[n] = *(const float4*)&Wsel[(size_t)n * KD + k];
#pragma unroll
            for (int t = 0; t < 8; ++t) {
                float4 xv = *(const float4*)&x[(size_t)(t0 + t) * KD + k];
#pragma unroll
                for (int n = 0; n < NPARTS; ++n)
                    acc[t][n] += xv.x * ws[n].x + xv.y * ws[n].y
                               + xv.z * ws[n].z + xv.w * ws[n].w;
            }
        }
#pragma unroll
        for (int s = 1; s < 64; s <<= 1)
#pragma unroll
            for (int t = 0; t < 8; ++t)
#pragma unroll
                for (int n = 0; n < NPARTS; ++n)
                    acc[t][n] += __shfl_xor(acc[t][n], s);
        if (lane == 0) {
#pragma unroll
            for (int t = 0; t < 8; ++t)
#pragma unroll
                for (int n = 0; n < NPARTS; ++n) {
                    float v = acc[t][n] + (kc == 0 ? bsel[n] : 0.f);
                    atomicAdd(&sxb[(size_t)(t0 + t) * NPARTS + n], v);
                }
        }

    } else {
        const int b4 = bid - 1024;
        const int fb = b4 >> 3, kc = b4 & 7;        // fb 0..13
        const int f0 = fb * 32 + w * 8;
        float acc[8][11];
#pragma unroll
        for (int t = 0; t < 8; ++t)
#pragma unroll
            for (int n = 0; n < 11; ++n) acc[t][n] = 0.f;

#pragma unroll
        for (int k4 = 0; k4 < 2; ++k4) {
            const int k = kc * 512 + k4 * 256 + lane * 4;
            float we[4][11];
#pragma unroll
            for (int j = 0; j < 4; ++j) {
#pragma unroll
                for (int n = 0; n < NPARTS; ++n)
                    we[j][n] = Wexp[(size_t)(k + j) * NPARTS + n];
                we[j][10] = bexp[k + j];
            }
#pragma unroll
            for (int t = 0; t < 8; ++t) {
                const int f = f0 + t;
                float4 xv = (f < NSF) ? *(const float4*)&Wfc[(size_t)f * KD + k]
                                      : make_float4(0.f, 0.f, 0.f, 0.f);
#pragma unroll
                for (int n = 0; n < 11; ++n)
                    acc[t][n] += xv.x * we[0][n] + xv.y * we[1][n]
                               + xv.z * we[2][n] + xv.w * we[3][n];
            }
        }
#pragma unroll
        for (int s = 1; s < 64; s <<= 1)
#pragma unroll
            for (int t = 0; t < 8; ++t)
#pragma unroll
                for (int n = 0; n < 11; ++n)
                    acc[t][n] += __shfl_xor(acc[t][n], s);
        if (lane == 0) {
#pragma unroll
            for (int t = 0; t < 8; ++t) {
                const int f = f0 + t;
                if (f < NSF) {
#pragma unroll
                    for (int n = 0; n < NPARTS; ++n)
                        atomicAdd(&gc[(size_t)f * 12 + n], acc[t][n]);
                    atomicAdd(&gc[(size_t)f * 12 + 10],
                              acc[t][10] + (kc == 0 ? bfc[f] : 0.f));
                }
            }
        }
    }
}

// ============ main: zero-LDS K-loop (T19-pinned), C-only epilogue ============
// (unchanged from R7 — write-scatter removed; stores dense C into out[:,0:410])
#define A_IDX(kt, mi, ks) ((((size_t)(tb * 2 + ((mi) >> 1)) * 64 + (size_t)(kt)) * 256 \
                            + ((ks) * 2 + ((mi) & 1)) * 64 + lane) * 8)
#define B_IDX(kt, nj, ks) (((size_t)(fb * 64 + (kt)) * 512 \
                            + (wf * 4 + (ks) * 2 + (nj)) * 64 + lane) * 8)

__global__ __launch_bounds__(256, 2) void main_kernel(const u16* __restrict__ xb,
                                                      const u16* __restrict__ bsw,
                                                      float* __restrict__ out) {
    // [mi][donor kh][row16][f pad 34]: stride 34 -> bank = (ml+8q)%32, 2-way = free
    __shared__ float red[4][4][16][34];   // 34.8 KB

    const int tid = threadIdx.x;
    const int f2 = blockIdx.x >> 6;     // 0..12  (f2=13 would be all fg>=410)
    const int tb = blockIdx.x & 63;     // 0..63  (64-token tiles)
    const int lane = tid & 63;
    const int kh = tid >> 6;            // K-split wave id 0..3
    const int q = lane >> 4, ml = lane & 15;
    const int fb = f2 >> 1, wf = f2 & 1;

    f32x4 acc[4][2];
#pragma unroll
    for (int mi = 0; mi < 4; ++mi)
#pragma unroll
        for (int nj = 0; nj < 2; ++nj) acc[mi][nj] = (f32x4){0.f,0.f,0.f,0.f};

    bf16x8 fa[4][4], fbv[4][2];

#define LOADAB(p, kt, ks) do {                                            \
        _Pragma("unroll")                                                 \
        for (int mi = 0; mi < 4; ++mi)                                    \
            fa[p][mi] = *(const bf16x8*)&xb[A_IDX((kt), mi, (ks))];       \
        _Pragma("unroll")                                                 \
        for (int nj = 0; nj < 2; ++nj)                                    \
            fbv[p][nj] = *(const bf16x8*)&bsw[B_IDX((kt), nj, (ks))];     \
    } while (0)

#define MFMAS(p) do {                                                     \
        _Pragma("unroll")                                                 \
        for (int mi = 0; mi < 4; ++mi)                                    \
            _Pragma("unroll")                                             \
            for (int nj = 0; nj < 2; ++nj)                                \
                acc[mi][nj] = __builtin_amdgcn_mfma_f32_16x16x32_bf16(    \
                    fa[p][mi], fbv[p][nj], acc[mi][nj], 0, 0, 0);         \
    } while (0)

    // half-step s in [0,32): kt = kh*16 + (s>>1), ks = s&1
#define LD(p, s) LOADAB((p), kh * 16 + ((s) >> 1), (s) & 1)

    LD(0, 0); LD(1, 1); LD(2, 2);
    __builtin_amdgcn_sched_group_barrier(0x020, 18, 0);   // prologue: 18 VMEM_READ first
#pragma unroll
    for (int s = 0; s < 32; ++s) {
        if (s + 3 < 32) LD((s + 3) & 3, s + 3);
        MFMAS(s & 3);
        if (s + 3 < 32)
            __builtin_amdgcn_sched_group_barrier(0x020, 6, 0);  // this step's prefetch
        __builtin_amdgcn_sched_group_barrier(0x008, 8, 0);      // this step's MFMAs
    }
#undef LD
#undef LOADAB
#undef MFMAS

    // ---- K-reduce: wave kh publishes partials; owns row group kh after barrier
#pragma unroll
    for (int mi = 0; mi < 4; ++mi)
#pragma unroll
        for (int nj = 0; nj < 2; ++nj)
#pragma unroll
            for (int r = 0; r < 4; ++r)
                red[mi][kh][q * 4 + r][nj * 16 + ml] = acc[mi][nj][r];
    __syncthreads();

    // ---- epilogue: store dense C rows (f32) into out[t][0..409] ----
#pragma unroll
    for (int nj = 0; nj < 2; ++nj) {
        const int fl = nj * 16 + ml;
        const int fg = f2 * 32 + fl;
        if (fg >= NSF) continue;
#pragma unroll
        for (int r = 0; r < 4; ++r) {
            const int tl = kh * 16 + q * 4 + r;
            const float v = red[kh][0][q * 4 + r][fl] + red[kh][1][q * 4 + r][fl]
                          + red[kh][2][q * 4 + r][fl] + red[kh][3][q * 4 + r][fl];
            out[(size_t)(tb * 64 + tl) * OUTF + fg] = v;
        }
    }
}

// ============ expand: out[t][j] = C[t][fg] + sx[t][n]*G[fg][n] + c[fg] =======
// (unchanged from R7 — dense float4 writes, no RMW)
__global__ __launch_bounds__(256) void expand(const float* __restrict__ sxb,
                                              const float* __restrict__ gc,
                                              float* out) {
    __shared__ float Ct[4][412];
    __shared__ float sxl[4][NPARTS];
    const int tid = threadIdx.x;
    const int t0 = blockIdx.x * 4;

    int   ns[4][4], fgs[4][4];
    float gv[4][4], cv[4][4];
#pragma unroll
    for (int g = 0; g < 4; ++g)
#pragma unroll
        for (int e = 0; e < 4; ++e) {
            const int j = g * 1024 + tid * 4 + e;
            const int n = j / NSF;                 // 0..9
            const int fg = j - n * NSF;
            ns[g][e] = n; fgs[g][e] = fg;
            gv[g][e] = gc[(size_t)fg * 12 + n];
            cv[g][e] = gc[(size_t)fg * 12 + 10];
        }

    for (int i = tid; i < 4 * NSF; i += 256)
        Ct[i / NSF][i % NSF] = out[(size_t)(t0 + i / NSF) * OUTF + (i % NSF)];
    if (tid < 4 * NPARTS)
        sxl[tid / NPARTS][tid % NPARTS] =
            sxb[(size_t)(t0 + tid / NPARTS) * NPARTS + tid % NPARTS];
    __syncthreads();

#pragma unroll
    for (int r = 0; r < 4; ++r) {
        float* orow = out + (size_t)(t0 + r) * OUTF;
#pragma unroll
        for (int g = 0; g < 4; ++g) {
            float4 v;
            v.x = Ct[r][fgs[g][0]] + sxl[r][ns[g][0]] * gv[g][0] + cv[g][0];
            v.y = Ct[r][fgs[g][1]] + sxl[r][ns[g][1]] * gv[g][1] + cv[g][1];
            v.z = Ct[r][fgs[g][2]] + sxl[r][ns[g][2]] * gv[g][2] + cv[g][2];
            v.w = Ct[r][fgs[g][3]] + sxl[r][ns[g][3]] * gv[g][3] + cv[g][3];
            *(float4*)&orow[g * 1024 + tid * 4] = v;
        }
    }
}

extern "C" void kernel_launch(void* const* d_in, const int* in_sizes, int n_in,
                              void* d_out, int out_size, void* d_ws, size_t ws_size,
                              hipStream_t stream) {
    const float* x    = (const float*)d_in[0];
    const float* Wsel = (const float*)d_in[1];
    const float* bsel = (const float*)d_in[2];
    const float* Wexp = (const float*)d_in[3];
    const float* bexp = (const float*)d_in[4];
    const float* Wfc  = (const float*)d_in[5];
    const float* bfc  = (const float*)d_in[6];
    float* out = (float*)d_out;

    char* ws = (char*)d_ws;
    u16* xb    = (u16*)(ws + WS_XB);
    u16* bsw   = (u16*)(ws + WS_BSW);
    float* sxb = (float*)(ws + WS_SX);
    float* gcv = (float*)(ws + WS_GC);

    // 1: retile x/Wfc to bf16 granule tiles + zero sx/gc accumulators
    retile<<<dim3(4096 + 448 + 1), dim3(256), 0, stream>>>(
        x, Wfc, xb, bsw, (uint4*)(ws + WS_SX));
    // 2: sx/G partials (K-split x8, atomic combine; x/Wfc L3-warm)
    selg<<<dim3(1024 + 112), dim3(256), 0, stream>>>(
        x, Wsel, bsel, Wexp, bexp, Wfc, bfc, sxb, gcv);
    // 3: GEMM -> dense C (first 410 cols of each out row)
    main_kernel<<<dim3(13 * 64), dim3(256), 0, stream>>>(xb, bsw, out);
    // 4: dense expansion out = C + sx*G + c
    expand<<<dim3(1024), dim3(256), 0, stream>>>(sxb, gcv, out);
}